// Round 13
// baseline (34.505 us; speedup 1.0000x reference)
//
#include <hip/hip_runtime.h>
#include <hip/hip_bf16.h>
#include <hip/hip_fp16.h>
#include <math.h>

#define B 512
#define M 24
#define F 128
#define NRBF 20
#define CUTOFF 5.0f
#define SA_LD 44    // shorts/rbf row (88B = 22dw, gcd 2 -> free 2-way)
#define SH_LD 140   // shorts/sH row (280B = 70dw, gcd 2 -> free 2-way)
#define GEO_LD 34   // uint2 per geo row (272B, 68dw -> groups land on distinct banks, 16B-aligned)
#define CHUNK 8

// Single kernel, one block = one molecule, 8 waves, 2 blocks/CU.
// MFMA backbone: P1 s@W1 -> h; P2 h@W2 -> phi (chunks 0,2); P3 rbf_ext@Wf_ext
// (k-slots 0..19 = sin(nkd)/d Chebyshev, slot 20 = mask, Wf row 20 = bf, so
// C = (rbf@Wf + bf)*mask, exactly 0 for invalid pairs).
// ROUND-13 RESTRUCTURE: i-interleaved A-rows kill the cross-lane j-reduction.
//   A-tile for (batch bb, tile mm): 16 rows = 4 i x 4 j, row = ii*4 + rr
//   holding pair (i = bb*4+ii, j = mm*4+rr). C-layout row = g*4+r -> lane
//   group g owns i = bb*4+g and its 4 regs are 4 j's OF ITS OWN i; summing
//   over the 8 mm-tiles in the VALU accumulator completes the j-sum with
//   ZERO shuffles (r12 spent 5 DS-shuffles per output row on this).
//   Each lane therefore needs phi[all 32 j][its f2]: P2 writes phi to LDS as
//   packed bf16 pairs; each lane broadcasts 32 dwords into registers once
//   (static indices only). Each lane stores all 4 components of its own i.
// Geo as half4, read 2 x b128 per mm (stride GEO_LD avoids group conflicts).
// dv_v * v term of the reference is identically zero (v^0 = 0).
// Fragment layouts (v_mfma_f32_16x16x32_bf16):
//   C/D: col = lane&15, row = (lane>>4)*4 + reg            [m89-verified]
//   A/B: row/col = lane&15, k = (e>>2)*16 + 4*(lane>>4)+(e&3)

typedef __attribute__((ext_vector_type(8))) short short8;
typedef __attribute__((ext_vector_type(4))) float f32x4;

#define KIDX(g, e) ((((e) >> 2) << 4) + 4 * (g) + ((e) & 3))

__device__ __forceinline__ unsigned f2bf(float x) {
    unsigned u = __builtin_bit_cast(unsigned, x);
    return (u + 0x7FFFu + ((u >> 16) & 1u)) >> 16;   // RNE bf16
}
__device__ __forceinline__ unsigned f2h(float x) {
    return (unsigned)__builtin_bit_cast(unsigned short, __float2half(x));
}

__device__ __forceinline__ short8 pack_frag(unsigned u0, unsigned u1,
                                            unsigned u2, unsigned u3) {
    uint4 t = make_uint4(u0, u1, u2, u3);
    return __builtin_bit_cast(short8, t);
}

// B-fragment from a global fp32 row-major matrix W[ld columns]
__device__ __forceinline__ short8 load_wfrag(const float* __restrict__ W, int ld,
                                             int col, int kbase, int g) {
    unsigned u[4];
#pragma unroll
    for (int q = 0; q < 4; ++q) {
        int k0 = kbase + KIDX(g, 2 * q);
        int k1 = kbase + KIDX(g, 2 * q + 1);
        u[q] = f2bf(W[(size_t)k0 * ld + col]) | (f2bf(W[(size_t)k1 * ld + col]) << 16);
    }
    return pack_frag(u[0], u[1], u[2], u[3]);
}

// B-fragment for the extended edge filter: rows 0..19 = Wf, row 20 = bf, rest 0
__device__ __forceinline__ short8 load_wffrag(const float* __restrict__ Wf,
                                              const float* __restrict__ bfv,
                                              int col, int g) {
    unsigned u[4];
#pragma unroll
    for (int q = 0; q < 4; ++q) {
        int k0 = KIDX(g, 2 * q);
        int k1 = KIDX(g, 2 * q + 1);
        float f0 = (k0 < NRBF) ? Wf[(size_t)k0 * (3 * F) + col] : (k0 == NRBF ? bfv[col] : 0.f);
        float f1 = (k1 < NRBF) ? Wf[(size_t)k1 * (3 * F) + col] : (k1 == NRBF ? bfv[col] : 0.f);
        u[q] = f2bf(f0) | (f2bf(f1) << 16);
    }
    return pack_frag(u[0], u[1], u[2], u[3]);
}

// A-fragment from LDS bf16 matrix with row stride `ldsh` shorts (k contiguous)
__device__ __forceinline__ short8 load_afrag(const short* sp, int row, int ldsh,
                                             int kbase, int g) {
    const short* p = sp + row * ldsh + kbase + 4 * g;
    uint2 lo = *(const uint2*)(p);
    uint2 hi = *(const uint2*)(p + 16);
    uint4 t = make_uint4(lo.x, lo.y, hi.x, hi.y);
    return __builtin_bit_cast(short8, t);
}

__global__ __launch_bounds__(512, 2) void painn_kernel(
    const int* __restrict__ atoms,
    const float* __restrict__ apos,
    const float* __restrict__ emb,
    const float* __restrict__ W1, const float* __restrict__ b1,
    const float* __restrict__ W2, const float* __restrict__ b2,
    const float* __restrict__ Wf, const float* __restrict__ bf,
    float* __restrict__ out)
{
    __shared__ __attribute__((aligned(16))) short sH[32 * SH_LD];
    __shared__ __attribute__((aligned(16))) short sA[2][CHUNK * 32 * SA_LD];
    __shared__ __attribute__((aligned(16))) unsigned sGeoH[2][CHUNK * GEO_LD * 2]; // half4 rhat
    __shared__ __attribute__((aligned(16))) unsigned sPhiP[32 * F];   // bf16(ph0)|bf16(ph2)<<16
    __shared__ __attribute__((aligned(16))) float sPos[M][4];

    const int tid  = threadIdx.x;
    const int b    = blockIdx.x;
    const int wid  = tid >> 6;
    const int lane = tid & 63;
    const int g    = lane >> 4;
    const int lrow = lane & 15;
    const int f2   = wid * 16 + lrow;

    const float kth = 3.14159265358979323846f / CUTOFF;

    // ---- P0: s (emb gather) -> sH bf16, zero pad rows, positions --------
    for (int idx = tid; idx < M * 32; idx += 512) {
        int node = idx >> 5;
        int f4 = idx & 31;
        int a = atoms[b * M + node];
        float4 v = reinterpret_cast<const float4*>(emb + (size_t)a * F)[f4];
        unsigned u0 = f2bf(v.x) | (f2bf(v.y) << 16);
        unsigned u1 = f2bf(v.z) | (f2bf(v.w) << 16);
        *reinterpret_cast<uint2*>(&sH[node * SH_LD + f4 * 4]) = make_uint2(u0, u1);
    }
    for (int t = tid; t < 560; t += 512)               // rows 24..31 = 0
        reinterpret_cast<unsigned*>(sH)[1680 + t] = 0u;
    if (tid < M * 3) sPos[tid / 3][tid % 3] = apos[(size_t)b * M * 3 + tid];
    __syncthreads();

    // ---- P1: h = silu(s @ W1 + b1), MFMA --------------------------------
    {
        float b1v = b1[f2];
        f32x4 c[2] = {{0.f, 0.f, 0.f, 0.f}, {0.f, 0.f, 0.f, 0.f}};
#pragma unroll
        for (int ks = 0; ks < 4; ++ks) {
            short8 bfrag = load_wfrag(W1, F, f2, ks * 32, g);
            short8 a0 = load_afrag(sH, lrow, SH_LD, ks * 32, g);
            short8 a1 = load_afrag(sH, 16 + lrow, SH_LD, ks * 32, g);
            c[0] = __builtin_amdgcn_mfma_f32_16x16x32_bf16(a0, bfrag, c[0], 0, 0, 0);
            c[1] = __builtin_amdgcn_mfma_f32_16x16x32_bf16(a1, bfrag, c[1], 0, 0, 0);
        }
        __syncthreads();   // all s reads done before overwriting sH with h
#pragma unroll
        for (int rt = 0; rt < 2; ++rt)
#pragma unroll
            for (int r = 0; r < 4; ++r) {
                int row = rt * 16 + g * 4 + r;
                float x = c[rt][r] + b1v;
                float h = x / (1.0f + __expf(-x));
                sH[row * SH_LD + f2] = (short)f2bf(h);
            }
    }
    __syncthreads();

    // ---- P2: phi chunks 0,2 = h @ W2 + b2 -> packed bf16 into sPhiP -----
    {
        float ph0v[8], ph2v[8];
#pragma unroll
        for (int half = 0; half < 2; ++half) {
            int wcol = half ? (256 + f2) : f2;
            float b2v = b2[wcol];
            f32x4 c[2] = {{0.f, 0.f, 0.f, 0.f}, {0.f, 0.f, 0.f, 0.f}};
#pragma unroll
            for (int ks = 0; ks < 4; ++ks) {
                short8 bfrag = load_wfrag(W2, 3 * F, wcol, ks * 32, g);
                short8 a0 = load_afrag(sH, lrow, SH_LD, ks * 32, g);
                short8 a1 = load_afrag(sH, 16 + lrow, SH_LD, ks * 32, g);
                c[0] = __builtin_amdgcn_mfma_f32_16x16x32_bf16(a0, bfrag, c[0], 0, 0, 0);
                c[1] = __builtin_amdgcn_mfma_f32_16x16x32_bf16(a1, bfrag, c[1], 0, 0, 0);
            }
#pragma unroll
            for (int rt = 0; rt < 2; ++rt)
#pragma unroll
                for (int r = 0; r < 4; ++r) {
                    if (half == 0) ph0v[rt * 4 + r] = c[rt][r] + b2v;
                    else           ph2v[rt * 4 + r] = c[rt][r] + b2v;
                }
        }
#pragma unroll
        for (int rt = 0; rt < 2; ++rt)
#pragma unroll
            for (int r = 0; r < 4; ++r) {
                int row = rt * 16 + g * 4 + r;
                sPhiP[row * F + f2] = f2bf(ph0v[rt * 4 + r]) | (f2bf(ph2v[rt * 4 + r]) << 16);
            }
    }

    // ---- P3: Wf fragments + pipelined produce/consume -------------------
    short8 wfrag0 = load_wffrag(Wf, bf, f2, g);
    short8 wfrag2 = load_wffrag(Wf, bf, 256 + f2, g);

    const int pil = tid >> 5;          // producer i-local 0..7 (tid<256)
    const int pj  = tid & 31;          // producer j 0..31

    unsigned pk[16];
    unsigned gxy, gz;

    auto produce = [&](int ic) {
#pragma unroll
        for (int q = 0; q < 16; ++q) pk[q] = 0u;
        gxy = 0u; gz = 0u;
        int i = ic * CHUNK + pil;
        if (pj < M && pj != i) {
            float dx = sPos[i][0] - sPos[pj][0];
            float dy = sPos[i][1] - sPos[pj][1];
            float dz = sPos[i][2] - sPos[pj][2];
            float d = sqrtf(dx * dx + dy * dy + dz * dz);
            if (d < CUTOFF) {
                float inv = 1.0f / d;
                float s1, c1;
                __sincosf(kth * d, &s1, &c1);
                float cc = 2.0f * c1;
                float vp = s1 * inv;               // sin(1*th)/d
                float vc = 2.0f * s1 * c1 * inv;   // sin(2*th)/d
                pk[0] = f2bf(vp) | (f2bf(vc) << 16);
#pragma unroll
                for (int q = 1; q < 10; ++q) {
                    float v3 = cc * vc - vp;
                    float v4 = cc * v3 - vc;
                    pk[q] = f2bf(v3) | (f2bf(v4) << 16);
                    vp = v3; vc = v4;
                }
                pk[10] = 0x3F80u;                  // k=20: mask = bf16(1.0)
                gxy = f2h(dx * inv) | (f2h(dy * inv) << 16);
                gz  = f2h(dz * inv);
            }
        }
    };
    auto writebuf = [&](int buf) {
        // i-interleaved A row: tile mm = pj>>2 holds (ii = pil&3, rr = pj&3)
        int arow = (pil >> 2) * 128 + (pj >> 2) * 16 + (pil & 3) * 4 + (pj & 3);
        short* rp = &sA[buf][arow * SA_LD];
#pragma unroll
        for (int q = 0; q < 8; ++q)
            *reinterpret_cast<uint2*>(rp + q * 4) = make_uint2(pk[2 * q], pk[2 * q + 1]);
        *reinterpret_cast<uint2*>(&sGeoH[buf][(pil * GEO_LD + pj) * 2]) = make_uint2(gxy, gz);
    };

    if (tid < 256) { produce(0); writebuf(0); }
    __syncthreads();   // covers sPhiP writes + sA/sGeo buf0

    // broadcast phi[all 32 j][f2] into 32 packed registers (static indices)
    unsigned php[32];
#pragma unroll
    for (int j = 0; j < 32; ++j) php[j] = sPhiP[j * F + f2];

    for (int ic = 0; ic < 3; ++ic) {
        const int buf = ic & 1;
        if (ic < 2 && tid < 256) { produce(ic + 1); writebuf(buf ^ 1); } // overlaps consume
#pragma unroll
        for (int bb = 0; bb < 2; ++bb) {
            const int iloc = bb * 4 + g;           // this lane-group's i
            const int i = ic * CHUNK + iloc;
            float s0 = 0.f, ax = 0.f, ay = 0.f, az = 0.f;
#pragma unroll
            for (int mm = 0; mm < 8; ++mm) {
                short8 afr = load_afrag(&sA[buf][0], bb * 128 + mm * 16 + lrow, SA_LD, 0, g);
                f32x4 z4 = {0.f, 0.f, 0.f, 0.f};
                f32x4 c0 = __builtin_amdgcn_mfma_f32_16x16x32_bf16(afr, wfrag0, z4, 0, 0, 0);
                f32x4 c2 = __builtin_amdgcn_mfma_f32_16x16x32_bf16(afr, wfrag2, z4, 0, 0, 0);
                const uint4* gp = reinterpret_cast<const uint4*>(
                    &sGeoH[buf][(iloc * GEO_LD + mm * 4) * 2]);
                uint4 ga = gp[0], gb = gp[1];      // j = mm*4 .. mm*4+3
#pragma unroll
                for (int r = 0; r < 4; ++r) {
                    unsigned pxy = (r == 0) ? ga.x : (r == 1) ? ga.z : (r == 2) ? gb.x : gb.z;
                    unsigned pzz = (r == 0) ? ga.y : (r == 1) ? ga.w : (r == 2) ? gb.y : gb.w;
                    __half2 hxy = __builtin_bit_cast(__half2, pxy);
                    float gx = __low2float(hxy);
                    float gy = __high2float(hxy);
                    float gzf = __low2float(__builtin_bit_cast(__half2, pzz));
                    unsigned pp = php[mm * 4 + r];
                    float p0 = __builtin_bit_cast(float, pp << 16);
                    float p2 = __builtin_bit_cast(float, pp & 0xFFFF0000u);
                    s0 = fmaf(c0[r], p0, s0);
                    float m2 = c2[r] * p2;
                    ax = fmaf(m2, gx, ax);
                    ay = fmaf(m2, gy, ay);
                    az = fmaf(m2, gzf, az);
                }
            }
            const int node = b * M + i;
            float* o = out + (size_t)node * (4 * F);
            o[f2] = emb[(size_t)atoms[node] * F + f2] + s0;
            o[F + 3 * f2 + 0] = ax;
            o[F + 3 * f2 + 1] = ay;
            o[F + 3 * f2 + 2] = az;
        }
        __syncthreads();
    }
}

extern "C" void kernel_launch(void* const* d_in, const int* in_sizes, int n_in,
                              void* d_out, int out_size, void* d_ws, size_t ws_size,
                              hipStream_t stream) {
    const int*   atoms = (const int*)d_in[0];
    const float* apos  = (const float*)d_in[1];
    // d_in[2] = graph_indexes (unused; batch structure is the fixed [B,M] layout)
    const float* emb = (const float*)d_in[3];
    const float* W1  = (const float*)d_in[4];
    const float* b1  = (const float*)d_in[5];
    const float* W2  = (const float*)d_in[6];
    const float* b2  = (const float*)d_in[7];
    const float* Wf  = (const float*)d_in[8];
    const float* bf  = (const float*)d_in[9];
    float* out = (float*)d_out;

    painn_kernel<<<B, 512, 0, stream>>>(atoms, apos, emb, W1, b1, W2, b2, Wf, bf, out);
}

// Round 14
// 30.235 us; speedup vs baseline: 1.1412x; 1.1412x over previous
//
#include <hip/hip_runtime.h>
#include <hip/hip_bf16.h>
#include <hip/hip_fp16.h>
#include <math.h>

#define B 512
#define M 24
#define F 128
#define NRBF 20
#define CUTOFF 5.0f
#define SA_LD 40    // shorts/rbf row, FRAGMENT-PACKED: 4 g-blocks x 8 shorts (80B, 16B-aligned)
#define SH_LD 140   // shorts/sH row (280B = 70dw, gcd 2 -> free 2-way)
#define CHUNK 8

// Single kernel, one block = one molecule, 8 waves, 2 blocks/CU. r12 structure
// (31.0us, best) + two DS cuts; r13's i-interleaved rows REVERTED (mm-stride
// 352dw = 0 mod 32 made producer writes 8-way bank-conflicted, 951K cycles).
//   P1 s@W1 -> h; P2 h@W2 -> phi chunks 0,2 (STAY IN REGISTERS);
//   P3 rbf_ext@Wf_ext per 8-i chunk, double-buffered produce/consume.
//   rbf_ext k: 0..19 = sin(nkd)/d (Chebyshev), 20 = mask, Wf row 20 = bf
//   -> C = (rbf@Wf+bf)*mask, exactly 0 for invalid pairs.
// DS cuts this round:
//   - A rows stored FRAGMENT-PACKED: g-block gb holds shorts k={4gb..4gb+3,
//     16+4gb..16+4gb+3} = uint4(pk[2gb],pk[2gb+1],pk[8+2gb],pk[8+2gb+1]).
//     Consumer A-fragment = ONE ds_read_b128 at row*40 + g*8 shorts.
//     Producer row write = 4 b128 (was 8 b64).
//   - geo read as uint4 pairs (2 half4 entries): 4 b128/il (was 8 b64).
// Reduction (r12-proven): 4x shfl_xor(32) pair-sum + ONE shfl_xor(send,16)
// value-rotation; group g stores its own component (g0=ds, g1/2/3=dv_xyz).
// dv_v * v term of the reference is identically zero (v^0 = 0).
// Fragment layouts (v_mfma_f32_16x16x32_bf16):
//   C/D: col = lane&15, row = (lane>>4)*4 + reg            [m89-verified]
//   A/B: row/col = lane&15, k = (e>>2)*16 + 4*(lane>>4)+(e&3)

typedef __attribute__((ext_vector_type(8))) short short8;
typedef __attribute__((ext_vector_type(4))) float f32x4;

#define KIDX(g, e) ((((e) >> 2) << 4) + 4 * (g) + ((e) & 3))

__device__ __forceinline__ unsigned f2bf(float x) {
    unsigned u = __builtin_bit_cast(unsigned, x);
    return (u + 0x7FFFu + ((u >> 16) & 1u)) >> 16;   // RNE bf16
}
__device__ __forceinline__ unsigned f2h(float x) {
    return (unsigned)__builtin_bit_cast(unsigned short, __float2half(x));
}

__device__ __forceinline__ short8 pack_frag(unsigned u0, unsigned u1,
                                            unsigned u2, unsigned u3) {
    uint4 t = make_uint4(u0, u1, u2, u3);
    return __builtin_bit_cast(short8, t);
}

// B-fragment from a global fp32 row-major matrix W[ld columns]
__device__ __forceinline__ short8 load_wfrag(const float* __restrict__ W, int ld,
                                             int col, int kbase, int g) {
    unsigned u[4];
#pragma unroll
    for (int q = 0; q < 4; ++q) {
        int k0 = kbase + KIDX(g, 2 * q);
        int k1 = kbase + KIDX(g, 2 * q + 1);
        u[q] = f2bf(W[(size_t)k0 * ld + col]) | (f2bf(W[(size_t)k1 * ld + col]) << 16);
    }
    return pack_frag(u[0], u[1], u[2], u[3]);
}

// B-fragment for the extended edge filter: rows 0..19 = Wf, row 20 = bf, rest 0
__device__ __forceinline__ short8 load_wffrag(const float* __restrict__ Wf,
                                              const float* __restrict__ bfv,
                                              int col, int g) {
    unsigned u[4];
#pragma unroll
    for (int q = 0; q < 4; ++q) {
        int k0 = KIDX(g, 2 * q);
        int k1 = KIDX(g, 2 * q + 1);
        float f0 = (k0 < NRBF) ? Wf[(size_t)k0 * (3 * F) + col] : (k0 == NRBF ? bfv[col] : 0.f);
        float f1 = (k1 < NRBF) ? Wf[(size_t)k1 * (3 * F) + col] : (k1 == NRBF ? bfv[col] : 0.f);
        u[q] = f2bf(f0) | (f2bf(f1) << 16);
    }
    return pack_frag(u[0], u[1], u[2], u[3]);
}

// A-fragment from LDS bf16 matrix with row stride `ldsh` shorts (k contiguous,
// KIDX gather) -- used for sH only
__device__ __forceinline__ short8 load_afrag(const short* sp, int row, int ldsh,
                                             int kbase, int g) {
    const short* p = sp + row * ldsh + kbase + 4 * g;
    uint2 lo = *(const uint2*)(p);
    uint2 hi = *(const uint2*)(p + 16);
    uint4 t = make_uint4(lo.x, lo.y, hi.x, hi.y);
    return __builtin_bit_cast(short8, t);
}

__global__ __launch_bounds__(512, 2) void painn_kernel(
    const int* __restrict__ atoms,
    const float* __restrict__ apos,
    const float* __restrict__ emb,
    const float* __restrict__ W1, const float* __restrict__ b1,
    const float* __restrict__ W2, const float* __restrict__ b2,
    const float* __restrict__ Wf, const float* __restrict__ bf,
    float* __restrict__ out)
{
    __shared__ __attribute__((aligned(16))) short sH[32 * SH_LD];
    __shared__ __attribute__((aligned(16))) short sA[2][CHUNK * 32 * SA_LD];
    __shared__ __attribute__((aligned(16))) unsigned sGeoH[2][CHUNK * 32 * 2]; // half4 rhat
    __shared__ __attribute__((aligned(16))) float sPos[M][4];

    const int tid  = threadIdx.x;
    const int b    = blockIdx.x;
    const int wid  = tid >> 6;
    const int lane = tid & 63;
    const int g    = lane >> 4;
    const int lrow = lane & 15;
    const int f2   = wid * 16 + lrow;

    const float kth = 3.14159265358979323846f / CUTOFF;

    // ---- P0: s (emb gather) -> sH bf16, zero pad rows, positions --------
    for (int idx = tid; idx < M * 32; idx += 512) {
        int node = idx >> 5;
        int f4 = idx & 31;
        int a = atoms[b * M + node];
        float4 v = reinterpret_cast<const float4*>(emb + (size_t)a * F)[f4];
        unsigned u0 = f2bf(v.x) | (f2bf(v.y) << 16);
        unsigned u1 = f2bf(v.z) | (f2bf(v.w) << 16);
        *reinterpret_cast<uint2*>(&sH[node * SH_LD + f4 * 4]) = make_uint2(u0, u1);
    }
    for (int t = tid; t < 560; t += 512)               // rows 24..31 = 0
        reinterpret_cast<unsigned*>(sH)[1680 + t] = 0u;
    if (tid < M * 3) sPos[tid / 3][tid % 3] = apos[(size_t)b * M * 3 + tid];
    __syncthreads();

    // ---- P1: h = silu(s @ W1 + b1), MFMA --------------------------------
    {
        float b1v = b1[f2];
        f32x4 c[2] = {{0.f, 0.f, 0.f, 0.f}, {0.f, 0.f, 0.f, 0.f}};
#pragma unroll
        for (int ks = 0; ks < 4; ++ks) {
            short8 bfrag = load_wfrag(W1, F, f2, ks * 32, g);
            short8 a0 = load_afrag(sH, lrow, SH_LD, ks * 32, g);
            short8 a1 = load_afrag(sH, 16 + lrow, SH_LD, ks * 32, g);
            c[0] = __builtin_amdgcn_mfma_f32_16x16x32_bf16(a0, bfrag, c[0], 0, 0, 0);
            c[1] = __builtin_amdgcn_mfma_f32_16x16x32_bf16(a1, bfrag, c[1], 0, 0, 0);
        }
        __syncthreads();   // all s reads done before overwriting sH with h
#pragma unroll
        for (int rt = 0; rt < 2; ++rt)
#pragma unroll
            for (int r = 0; r < 4; ++r) {
                int row = rt * 16 + g * 4 + r;
                float x = c[rt][r] + b1v;
                float h = x / (1.0f + __expf(-x));
                sH[row * SH_LD + f2] = (short)f2bf(h);
            }
    }
    __syncthreads();

    // ---- P2: phi chunks 0,2 = h @ W2 + b2; KEPT IN REGISTERS ------------
    float ph0[8], ph2[8];
#pragma unroll
    for (int half = 0; half < 2; ++half) {
        int wcol = half ? (256 + f2) : f2;
        float b2v = b2[wcol];
        f32x4 c[2] = {{0.f, 0.f, 0.f, 0.f}, {0.f, 0.f, 0.f, 0.f}};
#pragma unroll
        for (int ks = 0; ks < 4; ++ks) {
            short8 bfrag = load_wfrag(W2, 3 * F, wcol, ks * 32, g);
            short8 a0 = load_afrag(sH, lrow, SH_LD, ks * 32, g);
            short8 a1 = load_afrag(sH, 16 + lrow, SH_LD, ks * 32, g);
            c[0] = __builtin_amdgcn_mfma_f32_16x16x32_bf16(a0, bfrag, c[0], 0, 0, 0);
            c[1] = __builtin_amdgcn_mfma_f32_16x16x32_bf16(a1, bfrag, c[1], 0, 0, 0);
        }
#pragma unroll
        for (int rt = 0; rt < 2; ++rt)
#pragma unroll
            for (int r = 0; r < 4; ++r) {
                if (half == 0) ph0[rt * 4 + r] = c[rt][r] + b2v;
                else           ph2[rt * 4 + r] = c[rt][r] + b2v;
            }
    }
    // no barrier needed: phi never touches LDS

    // ---- P3: Wf fragments + pipelined produce/consume -------------------
    short8 wfrag0 = load_wffrag(Wf, bf, f2, g);
    short8 wfrag2 = load_wffrag(Wf, bf, 256 + f2, g);

    const int pil = tid >> 5;          // producer row 0..7 (tid<256)
    const int pj  = tid & 31;          // producer col 0..31

    unsigned pk[16];
    unsigned gxy, gz;

    auto produce = [&](int ic) {
#pragma unroll
        for (int q = 0; q < 16; ++q) pk[q] = 0u;
        gxy = 0u; gz = 0u;
        int i = ic * CHUNK + pil;
        if (pj < M && pj != i) {
            float dx = sPos[i][0] - sPos[pj][0];
            float dy = sPos[i][1] - sPos[pj][1];
            float dz = sPos[i][2] - sPos[pj][2];
            float d = sqrtf(dx * dx + dy * dy + dz * dz);
            if (d < CUTOFF) {
                float inv = 1.0f / d;
                float s1, c1;
                __sincosf(kth * d, &s1, &c1);
                float cc = 2.0f * c1;
                float vp = s1 * inv;               // sin(1*th)/d
                float vc = 2.0f * s1 * c1 * inv;   // sin(2*th)/d
                pk[0] = f2bf(vp) | (f2bf(vc) << 16);
#pragma unroll
                for (int q = 1; q < 10; ++q) {
                    float v3 = cc * vc - vp;
                    float v4 = cc * v3 - vc;
                    pk[q] = f2bf(v3) | (f2bf(v4) << 16);
                    vp = v3; vc = v4;
                }
                pk[10] = 0x3F80u;                  // k=20: mask = bf16(1.0)
                gxy = f2h(dx * inv) | (f2h(dy * inv) << 16);
                gz  = f2h(dz * inv);
            }
        }
    };
    auto writebuf = [&](int buf) {
        // fragment-packed row: g-block gb = shorts {4gb..4gb+3, 16+4gb..16+4gb+3}
        short* rp = &sA[buf][(pil * 32 + pj) * SA_LD];
#pragma unroll
        for (int gb = 0; gb < 4; ++gb)
            *reinterpret_cast<uint4*>(rp + gb * 8) =
                make_uint4(pk[2 * gb], pk[2 * gb + 1], pk[8 + 2 * gb], pk[8 + 2 * gb + 1]);
        *reinterpret_cast<uint2*>(&sGeoH[buf][(pil * 32 + pj) * 2]) = make_uint2(gxy, gz);
    };

    if (tid < 256) { produce(0); writebuf(0); }
    __syncthreads();

    for (int ic = 0; ic < 3; ++ic) {
        const int buf = ic & 1;
        if (ic < 2 && tid < 256) { produce(ic + 1); writebuf(buf ^ 1); } // overlaps consume
#pragma unroll 2
        for (int il = 0; il < CHUNK; ++il) {
            const int i = ic * CHUNK + il;
            float s0 = 0.f, ax = 0.f, ay = 0.f, az = 0.f;
#pragma unroll
            for (int rt = 0; rt < 2; ++rt) {
                // ONE b128: this (row, g)'s full A-fragment (packed layout)
                int row = il * 32 + rt * 16 + lrow;
                uint4 af = *reinterpret_cast<const uint4*>(&sA[buf][row * SA_LD + g * 8]);
                short8 afr = __builtin_bit_cast(short8, af);
                f32x4 z4 = {0.f, 0.f, 0.f, 0.f};
                f32x4 c0 = __builtin_amdgcn_mfma_f32_16x16x32_bf16(afr, wfrag0, z4, 0, 0, 0);
                f32x4 c2 = __builtin_amdgcn_mfma_f32_16x16x32_bf16(afr, wfrag2, z4, 0, 0, 0);
                // geo for j = rt*16+g*4 + {0..3}: two b128 (2 half4 pairs each)
                const uint4* gp = reinterpret_cast<const uint4*>(
                    &sGeoH[buf][(il * 32 + rt * 16 + g * 4) * 2]);
                uint4 ga = gp[0], gb = gp[1];
#pragma unroll
                for (int r = 0; r < 4; ++r) {
                    unsigned pxy = (r == 0) ? ga.x : (r == 1) ? ga.z : (r == 2) ? gb.x : gb.z;
                    unsigned pzz = (r == 0) ? ga.y : (r == 1) ? ga.w : (r == 2) ? gb.y : gb.w;
                    __half2 hxy = __builtin_bit_cast(__half2, pxy);
                    float gx = __low2float(hxy);
                    float gy = __high2float(hxy);
                    float gzf = __low2float(__builtin_bit_cast(__half2, pzz));
                    s0 = fmaf(c0[r], ph0[rt * 4 + r], s0);
                    float m2 = c2[r] * ph2[rt * 4 + r];
                    ax = fmaf(m2, gx, ax);
                    ay = fmaf(m2, gy, ay);
                    az = fmaf(m2, gzf, az);
                }
            }
            // stage 1: pair-sum over lane^32 (g^2)
            s0 += __shfl_xor(s0, 32);
            ax += __shfl_xor(ax, 32);
            ay += __shfl_xor(ay, 32);
            az += __shfl_xor(az, 32);
            // stage 2: ONE shuffle over lane^16 (g^1), value-rotated
            float keep = (g == 0) ? s0 : (g == 1) ? ax : (g == 2) ? ay : az;
            float send = (g == 0) ? ax : (g == 1) ? s0 : (g == 2) ? az : ay;
            float v = keep + __shfl_xor(send, 16);
            const int node = b * M + i;
            float outv = v;
            int col;
            if (g == 0) {
                outv += emb[(size_t)atoms[node] * F + f2];
                col = f2;
            } else {
                col = F + 3 * f2 + (g - 1);
            }
            out[(size_t)node * (4 * F) + col] = outv;
        }
        __syncthreads();
    }
}

extern "C" void kernel_launch(void* const* d_in, const int* in_sizes, int n_in,
                              void* d_out, int out_size, void* d_ws, size_t ws_size,
                              hipStream_t stream) {
    const int*   atoms = (const int*)d_in[0];
    const float* apos  = (const float*)d_in[1];
    // d_in[2] = graph_indexes (unused; batch structure is the fixed [B,M] layout)
    const float* emb = (const float*)d_in[3];
    const float* W1  = (const float*)d_in[4];
    const float* b1  = (const float*)d_in[5];
    const float* W2  = (const float*)d_in[6];
    const float* b2  = (const float*)d_in[7];
    const float* Wf  = (const float*)d_in[8];
    const float* bf  = (const float*)d_in[9];
    float* out = (float*)d_out;

    painn_kernel<<<B, 512, 0, stream>>>(atoms, apos, emb, W1, b1, W2, b2, Wf, bf, out);
}